// Round 14
// baseline (162.799 us; speedup 1.0000x reference)
//
#include <hip/hip_runtime.h>

#define HW    6400
#define CIN   256
#define HALF  128
#define QUART 64
#define NB    8
#define NE    5
#define PXT   64
#define NT    (HW / PXT)   // 100 tiles

typedef __attribute__((ext_vector_type(8))) short short8;
typedef __attribute__((ext_vector_type(4))) float f32x4;

__device__ __forceinline__ unsigned short f2bf(float f) {
    unsigned u = __builtin_bit_cast(unsigned, f);
    u = (u + 0x7FFFu + ((u >> 16) & 1u)) >> 16;   // RNE
    return (unsigned short)u;
}

// bw layout (shorts): [0,81920) Wrgb+I  [81920,163840) Wtir+I  [163840,204800) Wt1
__device__ __forceinline__ void prep_one(const float* __restrict__ Wrgb_f,
                                         const float* __restrict__ Wtir_f,
                                         const float* __restrict__ Wt1_f,
                                         unsigned short* __restrict__ bW, int i) {
    float v;
    if (i < 81920) {                       // Wrgb + I
        v = Wrgb_f[i];
        int m = i & 16383;
        if ((m >> 7) == (m & 127)) v += 1.0f;
    } else if (i < 163840) {               // Wtir + I
        int k = i - 81920;
        v = Wtir_f[k];
        int m = k & 16383;
        if ((m >> 7) == (m & 127)) v += 1.0f;
    } else {
        v = Wt1_f[i - 163840];
    }
    bW[i] = f2bf(v);
}

// ---------------- kernel 1: pack x -> bf16 frag-layout scratch + pool sums + weight prep
// scratch layout (shorts): half r at 0, half t at NB*NT*8192.
//   per (b,tile): 8192 shorts = frag-linear 128ch x 64px bf16 tile:
//   frag f = kt*4 + pt (kt=ch>>5, pt=(px>>4)&3), 512 shorts/frag;
//   short addr = f*512 + (((ch>>3)&3)*16 + (px&15))*8 + (ch&7)
// Pool blocks: 256 = (b in 8) x (cg in 32); each handles 8 consecutive channels
// (same kt, same lrow, ch&7 spans 0..7) -> one uint4 write per pixel.
__global__ void pack_pool_prep_kernel(const float* __restrict__ x,
                                      const float* __restrict__ Wrgb,
                                      const float* __restrict__ Wtir,
                                      const float* __restrict__ Wt1,
                                      float* __restrict__ pooled,
                                      unsigned short* __restrict__ bw,
                                      unsigned short* __restrict__ sc) {
    const int bid = blockIdx.x;
    const int t   = threadIdx.x;
    if (bid < NB * 32) {
        const int b  = bid >> 5, cg = bid & 31;
        const int c0 = cg * 8;                  // global channel base
        const int halfsel = c0 >> 7;            // 0 = r-half, 1 = t-half
        const int ch = c0 & 127;                // channel within half
        const int kt = ch >> 5, lrow = (ch >> 3) & 3;
        const float* xr[8];
#pragma unroll
        for (int j = 0; j < 8; ++j) xr[j] = x + ((size_t)b * CIN + c0 + j) * HW;
        unsigned short* scb = sc + (size_t)halfsel * NB * NT * 8192
                                 + (size_t)b * NT * 8192;
        float sum[8] = {0.f, 0.f, 0.f, 0.f, 0.f, 0.f, 0.f, 0.f};
        for (int px = t; px < HW; px += 256) {
            float v[8];
#pragma unroll
            for (int j = 0; j < 8; ++j) { v[j] = xr[j][px]; sum[j] += v[j]; }
            unsigned pk[4];
#pragma unroll
            for (int j = 0; j < 4; ++j)
                pk[j] = (unsigned)f2bf(v[2 * j]) | ((unsigned)f2bf(v[2 * j + 1]) << 16);
            int tile = px >> 6, pt = (px >> 4) & 3;
            size_t so = (size_t)tile * 8192 + (size_t)(kt * 4 + pt) * 512
                      + (size_t)(lrow * 16 + (px & 15)) * 8;
            *reinterpret_cast<uint4*>(&scb[so]) = make_uint4(pk[0], pk[1], pk[2], pk[3]);
        }
#pragma unroll
        for (int j = 0; j < 8; ++j)
            for (int off = 32; off > 0; off >>= 1)
                sum[j] += __shfl_down(sum[j], off, 64);
        __shared__ float pls[4][8];
        int wv = t >> 6, ln = t & 63;
        if (ln == 0) {
#pragma unroll
            for (int j = 0; j < 8; ++j) pls[wv][j] = sum[j];
        }
        __syncthreads();
        if (t < 8)
            pooled[b * CIN + c0 + t] = pls[0][t] + pls[1][t] + pls[2][t] + pls[3][t];
    } else {
        int i0 = (bid - NB * 32) * 1024 + t;
#pragma unroll
        for (int j = 0; j < 4; ++j)
            prep_one(Wrgb, Wtir, Wt1, bw, i0 + j * 256);
    }
}

// ---------------- kernel 2: gate (wave 0) + selected-expert MFMA, 64-px tiles --------
__launch_bounds__(256, 4)
__global__ void expert_kernel(const unsigned short* __restrict__ sc,
                              const unsigned short* __restrict__ bW,
                              const float* __restrict__ brgb, const float* __restrict__ btir,
                              const float* __restrict__ bt1,
                              const float* __restrict__ Wt2, const float* __restrict__ bt2,
                              const float* __restrict__ pooled,
                              const float* __restrict__ Wg, const float* __restrict__ bg,
                              float* __restrict__ out) {
    __shared__ unsigned short lxr[8192];   // 16 KiB: xr frags -> Dr bf16
    __shared__ unsigned short lxt[8192];   // 16 KiB: xt frags -> Dt bf16
    __shared__ float psum[512];
    __shared__ float sfin[128];            // sigmoid r [0,64) / t [64,128)
    __shared__ int   se;

    const int b    = blockIdx.y;
    const int p0   = blockIdx.x * PXT;
    const int t    = threadIdx.x;
    const int w    = __builtin_amdgcn_readfirstlane(t >> 6);
    const int lane = t & 63;
    const int lo   = lane & 15, hi = lane >> 4;

    // ---- stage scratch -> LDS: pure linear copy, 8x uint4 per thread ----
    {
        const unsigned short* srcr = sc + (size_t)b * NT * 8192 + (size_t)blockIdx.x * 8192;
        const unsigned short* srct = srcr + (size_t)NB * NT * 8192;
#pragma unroll
        for (int i = 0; i < 4; ++i) {
            int o = (i * 256 + t) * 8;
            *reinterpret_cast<uint4*>(&lxr[o]) = *reinterpret_cast<const uint4*>(&srcr[o]);
            *reinterpret_cast<uint4*>(&lxt[o]) = *reinterpret_cast<const uint4*>(&srct[o]);
        }
    }

    // ---- gate on wave 0 (redundant per block; pooled holds raw sums) ----
    if (t < 64) {
        float pv[4];
#pragma unroll
        for (int j = 0; j < 4; ++j) pv[j] = pooled[b * CIN + t * 4 + j] * (1.0f / HW);
        float best = -1e30f; int bi = 0;
        for (int e = 0; e < NE; ++e) {
            float part = 0.f;
#pragma unroll
            for (int j = 0; j < 4; ++j) part += pv[j] * Wg[e * CIN + t * 4 + j];
            for (int off = 32; off > 0; off >>= 1) part += __shfl_down(part, off, 64);
            part = __shfl(part, 0, 64);
            float logit = part + bg[e];
            if (logit > best) { best = logit; bi = e; }  // strict > == jnp.argmax
        }
        if (t == 0) se = bi;
    }
    __syncthreads();                       // staging + gate visible

    const int e = __builtin_amdgcn_readfirstlane(se);
    const unsigned short* bWrgb = bW + (size_t)e * 16384;
    const unsigned short* bWtir = bW + 81920 + (size_t)e * 16384;
    const unsigned short* bWt1  = bW + 163840 + (size_t)e * 8192;

    // ---- Dr = (Wrgb+I)@xr, Dt = (Wtir+I)@xt ----
    f32x4 cr[2][4], ct[2][4];
    {
        f32x4 z = {0.f, 0.f, 0.f, 0.f};
#pragma unroll
        for (int i = 0; i < 2; ++i)
#pragma unroll
            for (int j = 0; j < 4; ++j) { cr[i][j] = z; ct[i][j] = z; }
    }
#pragma unroll
    for (int kt = 0; kt < 4; ++kt) {
        short8 bR[4], bT[4];
#pragma unroll
        for (int pt = 0; pt < 4; ++pt) {
            bR[pt] = *reinterpret_cast<const short8*>(&lxr[(kt * 4 + pt) * 512 + lane * 8]);
            bT[pt] = *reinterpret_cast<const short8*>(&lxt[(kt * 4 + pt) * 512 + lane * 8]);
        }
#pragma unroll
        for (int rt = 0; rt < 2; ++rt) {
            int row = w * 32 + rt * 16 + lo;
            short8 aR = *reinterpret_cast<const short8*>(&bWrgb[row * 128 + kt * 32 + hi * 8]);
            short8 aT = *reinterpret_cast<const short8*>(&bWtir[row * 128 + kt * 32 + hi * 8]);
#pragma unroll
            for (int pt = 0; pt < 4; ++pt) {
                cr[rt][pt] = __builtin_amdgcn_mfma_f32_16x16x32_bf16(aR, bR[pt], cr[rt][pt], 0, 0, 0);
                ct[rt][pt] = __builtin_amdgcn_mfma_f32_16x16x32_bf16(aT, bT[pt], ct[rt][pt], 0, 0, 0);
            }
        }
    }

    // ---- D += bias (fp32), pack bf16 ----
    uint2 dbr[2][4], dbt[2][4];
#pragma unroll
    for (int rt = 0; rt < 2; ++rt) {
        int r0c = w * 32 + rt * 16 + hi * 4;
        f32x4 biasR = *reinterpret_cast<const f32x4*>(&brgb[e * HALF + r0c]);
        f32x4 biasT = *reinterpret_cast<const f32x4*>(&btir[e * HALF + r0c]);
#pragma unroll
        for (int pt = 0; pt < 4; ++pt) {
#pragma unroll
            for (int rg = 0; rg < 4; ++rg) {
                cr[rt][pt][rg] += biasR[rg];
                ct[rt][pt][rg] += biasT[rg];
            }
            dbr[rt][pt] = make_uint2(
                (unsigned)f2bf(cr[rt][pt][0]) | ((unsigned)f2bf(cr[rt][pt][1]) << 16),
                (unsigned)f2bf(cr[rt][pt][2]) | ((unsigned)f2bf(cr[rt][pt][3]) << 16));
            dbt[rt][pt] = make_uint2(
                (unsigned)f2bf(ct[rt][pt][0]) | ((unsigned)f2bf(ct[rt][pt][1]) << 16),
                (unsigned)f2bf(ct[rt][pt][2]) | ((unsigned)f2bf(ct[rt][pt][3]) << 16));
        }
    }
    __syncthreads();                                   // all GEMM1 B-frag reads done
#pragma unroll
    for (int rt = 0; rt < 2; ++rt) {
        int r0c = w * 32 + rt * 16 + hi * 4;
        int kt2 = r0c >> 5;
        int lp8 = (((r0c >> 3) & 3) * 16 + lo) * 8 + (r0c & 7);
#pragma unroll
        for (int pt = 0; pt < 4; ++pt) {
            int si = (kt2 * 4 + pt) * 512 + lp8;
            *reinterpret_cast<uint2*>(&lxr[si]) = dbr[rt][pt];
            *reinterpret_cast<uint2*>(&lxt[si]) = dbt[rt][pt];
        }
    }
    __syncthreads();                                   // Dr/Dt bf16 visible

    // ---- h = relu(Wt1@D + bt1), fragments in registers ----
    f32x4 chr[4], cht[4];
    {
        f32x4 z = {0.f, 0.f, 0.f, 0.f};
#pragma unroll
        for (int j = 0; j < 4; ++j) { chr[j] = z; cht[j] = z; }
    }
#pragma unroll
    for (int kt = 0; kt < 4; ++kt) {
        int row = w * 16 + lo;
        short8 aH = *reinterpret_cast<const short8*>(&bWt1[row * 128 + kt * 32 + hi * 8]);
#pragma unroll
        for (int pt = 0; pt < 4; ++pt) {
            short8 bDr = *reinterpret_cast<const short8*>(&lxr[(kt * 4 + pt) * 512 + lane * 8]);
            short8 bDt = *reinterpret_cast<const short8*>(&lxt[(kt * 4 + pt) * 512 + lane * 8]);
            chr[pt] = __builtin_amdgcn_mfma_f32_16x16x32_bf16(aH, bDr, chr[pt], 0, 0, 0);
            cht[pt] = __builtin_amdgcn_mfma_f32_16x16x32_bf16(aH, bDt, cht[pt], 0, 0, 0);
        }
    }

    // ---- Wt2·h in-register: 4 FMA + butterfly over hi, psum over waves ----
    {
        int m0 = w * 16 + hi * 4;
        f32x4 b1  = *reinterpret_cast<const f32x4*>(&bt1[e * QUART + m0]);
        f32x4 w2v = *reinterpret_cast<const f32x4*>(&Wt2[e * QUART + m0]);
#pragma unroll
        for (int pt = 0; pt < 4; ++pt) {
            float pr = 0.f, ptt = 0.f;
#pragma unroll
            for (int rg = 0; rg < 4; ++rg) {
                pr  = fmaf(w2v[rg], fmaxf(chr[pt][rg] + b1[rg], 0.f), pr);
                ptt = fmaf(w2v[rg], fmaxf(cht[pt][rg] + b1[rg], 0.f), ptt);
            }
            pr  += __shfl_xor(pr, 16, 64);  pr  += __shfl_xor(pr, 32, 64);
            ptt += __shfl_xor(ptt, 16, 64); ptt += __shfl_xor(ptt, 32, 64);
            if (hi == 0) {
                psum[w * 64 + pt * 16 + lo]       = pr;
                psum[256 + w * 64 + pt * 16 + lo] = ptt;
            }
        }
    }
    __syncthreads();
    if (t < 128) {
        int ph = t >> 6, px = t & 63;
        const float* ps = &psum[ph * 256];
        float a = ps[px] + ps[64 + px] + ps[128 + px] + ps[192 + px] + bt2[e];
        sfin[t] = 1.f / (1.f + __expf(-a));
    }
    __syncthreads();

    // ---- out = s_r*Dr + s_t*Dt (D fp32 still in accumulators) ----
#pragma unroll
    for (int rt = 0; rt < 2; ++rt) {
        int r0c = w * 32 + rt * 16 + hi * 4;
#pragma unroll
        for (int pt = 0; pt < 4; ++pt) {
            int pxb = pt * 16 + lo;
            float sr = sfin[pxb], st = sfin[64 + pxb];
            float* op = out + ((size_t)b * HALF + r0c) * HW + p0 + pxb;
#pragma unroll
            for (int rg = 0; rg < 4; ++rg)
                op[(size_t)rg * HW] = sr * cr[rt][pt][rg] + st * ct[rt][pt][rg];
        }
    }
}

extern "C" void kernel_launch(void* const* d_in, const int* in_sizes, int n_in,
                              void* d_out, int out_size, void* d_ws, size_t ws_size,
                              hipStream_t stream) {
    const float* x    = (const float*)d_in[0];
    const float* Wg   = (const float*)d_in[1];
    const float* bg   = (const float*)d_in[2];
    const float* Wrgb = (const float*)d_in[3];
    const float* brgb = (const float*)d_in[4];
    const float* Wtir = (const float*)d_in[5];
    const float* btir = (const float*)d_in[6];
    const float* Wt1  = (const float*)d_in[7];
    const float* bt1  = (const float*)d_in[8];
    const float* Wt2  = (const float*)d_in[9];
    const float* bt2  = (const float*)d_in[10];
    float* out = (float*)d_out;

    float*          pooled = (float*)d_ws;                              // 8 KiB raw sums
    unsigned short* bw     = (unsigned short*)((char*)d_ws + 8192);     // 400 KiB bf16 weights
    unsigned short* sc     = (unsigned short*)((char*)d_ws + 417792);   // 25 MiB bf16 x frags

    pack_pool_prep_kernel<<<NB * 32 + 200, 256, 0, stream>>>(x, Wrgb, Wtir, Wt1,
                                                             pooled, bw, sc);
    dim3 grid(NT, NB);
    expert_kernel<<<grid, 256, 0, stream>>>(sc, bw, brgb, btir, bt1, Wt2, bt2,
                                            pooled, Wg, bg, out);
}

// Round 15
// 146.403 us; speedup vs baseline: 1.1120x; 1.1120x over previous
//
#include <hip/hip_runtime.h>

#define HW    6400
#define CIN   256
#define HALF  128
#define QUART 64
#define NB    8
#define NE    5
#define PXT   64
#define NT    (HW / PXT)   // 100 tiles
#define NSEG  25           // px segments of 256 for the pack kernel
#define NPACK (NB * 32 * NSEG)   // 6400 pack blocks

typedef __attribute__((ext_vector_type(8))) short short8;
typedef __attribute__((ext_vector_type(4))) float f32x4;

__device__ __forceinline__ unsigned short f2bf(float f) {
    unsigned u = __builtin_bit_cast(unsigned, f);
    u = (u + 0x7FFFu + ((u >> 16) & 1u)) >> 16;   // RNE
    return (unsigned short)u;
}

// bw layout (shorts): [0,81920) Wrgb+I  [81920,163840) Wtir+I  [163840,204800) Wt1
__device__ __forceinline__ void prep_one(const float* __restrict__ Wrgb_f,
                                         const float* __restrict__ Wtir_f,
                                         const float* __restrict__ Wt1_f,
                                         unsigned short* __restrict__ bW, int i) {
    float v;
    if (i < 81920) {                       // Wrgb + I
        v = Wrgb_f[i];
        int m = i & 16383;
        if ((m >> 7) == (m & 127)) v += 1.0f;
    } else if (i < 163840) {               // Wtir + I
        int k = i - 81920;
        v = Wtir_f[k];
        int m = k & 16383;
        if ((m >> 7) == (m & 127)) v += 1.0f;
    } else {
        v = Wt1_f[i - 163840];
    }
    bW[i] = f2bf(v);
}

// ---------------- kernel 1: pack x -> bf16 frag scratch + pool sums + weight prep ----
// One pixel per thread; 6400 pack blocks (b, cg, seg) + 200 prep blocks.
// scratch layout (shorts): half r at 0, half t at NB*NT*8192.
//   per (b,tile): 8192 shorts = frag-linear 128ch x 64px bf16 tile:
//   frag f = kt*4 + pt (kt=ch>>5, pt=(px>>4)&3), 512 shorts/frag;
//   short addr = f*512 + (((ch>>3)&3)*16 + (px&15))*8 + (ch&7)
__global__ void pack_pool_prep_kernel(const float* __restrict__ x,
                                      const float* __restrict__ Wrgb,
                                      const float* __restrict__ Wtir,
                                      const float* __restrict__ Wt1,
                                      float* __restrict__ pooled,
                                      unsigned short* __restrict__ bw,
                                      unsigned short* __restrict__ sc) {
    const int bid = blockIdx.x;
    const int t   = threadIdx.x;
    if (bid < NPACK) {
        const int b   = bid / (32 * NSEG);
        const int rem = bid - b * (32 * NSEG);
        const int cg  = rem / NSEG;
        const int seg = rem - cg * NSEG;
        const int c0  = cg * 8;                 // global channel base (8 consecutive)
        const int halfsel = c0 >> 7;
        const int ch  = c0 & 127;
        const int kt  = ch >> 5, lrow = (ch >> 3) & 3;
        const int px  = seg * 256 + t;          // exactly one pixel per thread

        const float* xb = x + ((size_t)b * CIN + c0) * HW + px;
        float v[8];
#pragma unroll
        for (int j = 0; j < 8; ++j) v[j] = xb[(size_t)j * HW];

        unsigned pk[4];
#pragma unroll
        for (int j = 0; j < 4; ++j)
            pk[j] = (unsigned)f2bf(v[2 * j]) | ((unsigned)f2bf(v[2 * j + 1]) << 16);
        int tile = px >> 6, pt = (px >> 4) & 3;
        unsigned short* scb = sc + (size_t)halfsel * NB * NT * 8192
                                 + (size_t)b * NT * 8192;
        size_t so = (size_t)tile * 8192 + (size_t)(kt * 4 + pt) * 512
                  + (size_t)(lrow * 16 + (px & 15)) * 8;
        *reinterpret_cast<uint4*>(&scb[so]) = make_uint4(pk[0], pk[1], pk[2], pk[3]);

        // block-reduce the 8 channel sums, one atomicAdd each
        float s[8];
#pragma unroll
        for (int j = 0; j < 8; ++j) {
            s[j] = v[j];
            for (int off = 32; off > 0; off >>= 1)
                s[j] += __shfl_down(s[j], off, 64);
        }
        __shared__ float pls[4][8];
        int wv = t >> 6, ln = t & 63;
        if (ln == 0) {
#pragma unroll
            for (int j = 0; j < 8; ++j) pls[wv][j] = s[j];
        }
        __syncthreads();
        if (t < 8)
            atomicAdd(&pooled[b * CIN + c0 + t],
                      pls[0][t] + pls[1][t] + pls[2][t] + pls[3][t]);
    } else {
        int i0 = (bid - NPACK) * 1024 + t;
#pragma unroll
        for (int j = 0; j < 4; ++j)
            prep_one(Wrgb, Wtir, Wt1, bw, i0 + j * 256);
    }
}

// ---------------- kernel 2: gate (wave 0) + selected-expert MFMA, 64-px tiles --------
__launch_bounds__(256, 4)
__global__ void expert_kernel(const unsigned short* __restrict__ sc,
                              const unsigned short* __restrict__ bW,
                              const float* __restrict__ brgb, const float* __restrict__ btir,
                              const float* __restrict__ bt1,
                              const float* __restrict__ Wt2, const float* __restrict__ bt2,
                              const float* __restrict__ pooled,
                              const float* __restrict__ Wg, const float* __restrict__ bg,
                              float* __restrict__ out) {
    __shared__ unsigned short lxr[8192];   // 16 KiB: xr frags -> Dr bf16
    __shared__ unsigned short lxt[8192];   // 16 KiB: xt frags -> Dt bf16
    __shared__ float psum[512];
    __shared__ float sfin[128];            // sigmoid r [0,64) / t [64,128)
    __shared__ int   se;

    const int b    = blockIdx.y;
    const int p0   = blockIdx.x * PXT;
    const int t    = threadIdx.x;
    const int w    = __builtin_amdgcn_readfirstlane(t >> 6);
    const int lane = t & 63;
    const int lo   = lane & 15, hi = lane >> 4;

    // ---- stage scratch -> LDS: pure linear copy, 8x uint4 per thread ----
    {
        const unsigned short* srcr = sc + (size_t)b * NT * 8192 + (size_t)blockIdx.x * 8192;
        const unsigned short* srct = srcr + (size_t)NB * NT * 8192;
#pragma unroll
        for (int i = 0; i < 4; ++i) {
            int o = (i * 256 + t) * 8;
            *reinterpret_cast<uint4*>(&lxr[o]) = *reinterpret_cast<const uint4*>(&srcr[o]);
            *reinterpret_cast<uint4*>(&lxt[o]) = *reinterpret_cast<const uint4*>(&srct[o]);
        }
    }

    // ---- gate on wave 0 (redundant per block; pooled holds raw sums) ----
    if (t < 64) {
        float pv[4];
#pragma unroll
        for (int j = 0; j < 4; ++j) pv[j] = pooled[b * CIN + t * 4 + j] * (1.0f / HW);
        float best = -1e30f; int bi = 0;
        for (int e = 0; e < NE; ++e) {
            float part = 0.f;
#pragma unroll
            for (int j = 0; j < 4; ++j) part += pv[j] * Wg[e * CIN + t * 4 + j];
            for (int off = 32; off > 0; off >>= 1) part += __shfl_down(part, off, 64);
            part = __shfl(part, 0, 64);
            float logit = part + bg[e];
            if (logit > best) { best = logit; bi = e; }  // strict > == jnp.argmax
        }
        if (t == 0) se = bi;
    }
    __syncthreads();                       // staging + gate visible

    const int e = __builtin_amdgcn_readfirstlane(se);
    const unsigned short* bWrgb = bW + (size_t)e * 16384;
    const unsigned short* bWtir = bW + 81920 + (size_t)e * 16384;
    const unsigned short* bWt1  = bW + 163840 + (size_t)e * 8192;

    // ---- Dr = (Wrgb+I)@xr, Dt = (Wtir+I)@xt ----
    f32x4 cr[2][4], ct[2][4];
    {
        f32x4 z = {0.f, 0.f, 0.f, 0.f};
#pragma unroll
        for (int i = 0; i < 2; ++i)
#pragma unroll
            for (int j = 0; j < 4; ++j) { cr[i][j] = z; ct[i][j] = z; }
    }
#pragma unroll
    for (int kt = 0; kt < 4; ++kt) {
        short8 bR[4], bT[4];
#pragma unroll
        for (int pt = 0; pt < 4; ++pt) {
            bR[pt] = *reinterpret_cast<const short8*>(&lxr[(kt * 4 + pt) * 512 + lane * 8]);
            bT[pt] = *reinterpret_cast<const short8*>(&lxt[(kt * 4 + pt) * 512 + lane * 8]);
        }
#pragma unroll
        for (int rt = 0; rt < 2; ++rt) {
            int row = w * 32 + rt * 16 + lo;
            short8 aR = *reinterpret_cast<const short8*>(&bWrgb[row * 128 + kt * 32 + hi * 8]);
            short8 aT = *reinterpret_cast<const short8*>(&bWtir[row * 128 + kt * 32 + hi * 8]);
#pragma unroll
            for (int pt = 0; pt < 4; ++pt) {
                cr[rt][pt] = __builtin_amdgcn_mfma_f32_16x16x32_bf16(aR, bR[pt], cr[rt][pt], 0, 0, 0);
                ct[rt][pt] = __builtin_amdgcn_mfma_f32_16x16x32_bf16(aT, bT[pt], ct[rt][pt], 0, 0, 0);
            }
        }
    }

    // ---- D += bias (fp32), pack bf16 ----
    uint2 dbr[2][4], dbt[2][4];
#pragma unroll
    for (int rt = 0; rt < 2; ++rt) {
        int r0c = w * 32 + rt * 16 + hi * 4;
        f32x4 biasR = *reinterpret_cast<const f32x4*>(&brgb[e * HALF + r0c]);
        f32x4 biasT = *reinterpret_cast<const f32x4*>(&btir[e * HALF + r0c]);
#pragma unroll
        for (int pt = 0; pt < 4; ++pt) {
#pragma unroll
            for (int rg = 0; rg < 4; ++rg) {
                cr[rt][pt][rg] += biasR[rg];
                ct[rt][pt][rg] += biasT[rg];
            }
            dbr[rt][pt] = make_uint2(
                (unsigned)f2bf(cr[rt][pt][0]) | ((unsigned)f2bf(cr[rt][pt][1]) << 16),
                (unsigned)f2bf(cr[rt][pt][2]) | ((unsigned)f2bf(cr[rt][pt][3]) << 16));
            dbt[rt][pt] = make_uint2(
                (unsigned)f2bf(ct[rt][pt][0]) | ((unsigned)f2bf(ct[rt][pt][1]) << 16),
                (unsigned)f2bf(ct[rt][pt][2]) | ((unsigned)f2bf(ct[rt][pt][3]) << 16));
        }
    }
    __syncthreads();                                   // all GEMM1 B-frag reads done
#pragma unroll
    for (int rt = 0; rt < 2; ++rt) {
        int r0c = w * 32 + rt * 16 + hi * 4;
        int kt2 = r0c >> 5;
        int lp8 = (((r0c >> 3) & 3) * 16 + lo) * 8 + (r0c & 7);
#pragma unroll
        for (int pt = 0; pt < 4; ++pt) {
            int si = (kt2 * 4 + pt) * 512 + lp8;
            *reinterpret_cast<uint2*>(&lxr[si]) = dbr[rt][pt];
            *reinterpret_cast<uint2*>(&lxt[si]) = dbt[rt][pt];
        }
    }
    __syncthreads();                                   // Dr/Dt bf16 visible

    // ---- h = relu(Wt1@D + bt1), fragments in registers ----
    f32x4 chr[4], cht[4];
    {
        f32x4 z = {0.f, 0.f, 0.f, 0.f};
#pragma unroll
        for (int j = 0; j < 4; ++j) { chr[j] = z; cht[j] = z; }
    }
#pragma unroll
    for (int kt = 0; kt < 4; ++kt) {
        int row = w * 16 + lo;
        short8 aH = *reinterpret_cast<const short8*>(&bWt1[row * 128 + kt * 32 + hi * 8]);
#pragma unroll
        for (int pt = 0; pt < 4; ++pt) {
            short8 bDr = *reinterpret_cast<const short8*>(&lxr[(kt * 4 + pt) * 512 + lane * 8]);
            short8 bDt = *reinterpret_cast<const short8*>(&lxt[(kt * 4 + pt) * 512 + lane * 8]);
            chr[pt] = __builtin_amdgcn_mfma_f32_16x16x32_bf16(aH, bDr, chr[pt], 0, 0, 0);
            cht[pt] = __builtin_amdgcn_mfma_f32_16x16x32_bf16(aH, bDt, cht[pt], 0, 0, 0);
        }
    }

    // ---- Wt2·h in-register: 4 FMA + butterfly over hi, psum over waves ----
    {
        int m0 = w * 16 + hi * 4;
        f32x4 b1  = *reinterpret_cast<const f32x4*>(&bt1[e * QUART + m0]);
        f32x4 w2v = *reinterpret_cast<const f32x4*>(&Wt2[e * QUART + m0]);
#pragma unroll
        for (int pt = 0; pt < 4; ++pt) {
            float pr = 0.f, ptt = 0.f;
#pragma unroll
            for (int rg = 0; rg < 4; ++rg) {
                pr  = fmaf(w2v[rg], fmaxf(chr[pt][rg] + b1[rg], 0.f), pr);
                ptt = fmaf(w2v[rg], fmaxf(cht[pt][rg] + b1[rg], 0.f), ptt);
            }
            pr  += __shfl_xor(pr, 16, 64);  pr  += __shfl_xor(pr, 32, 64);
            ptt += __shfl_xor(ptt, 16, 64); ptt += __shfl_xor(ptt, 32, 64);
            if (hi == 0) {
                psum[w * 64 + pt * 16 + lo]       = pr;
                psum[256 + w * 64 + pt * 16 + lo] = ptt;
            }
        }
    }
    __syncthreads();
    if (t < 128) {
        int ph = t >> 6, px = t & 63;
        const float* ps = &psum[ph * 256];
        float a = ps[px] + ps[64 + px] + ps[128 + px] + ps[192 + px] + bt2[e];
        sfin[t] = 1.f / (1.f + __expf(-a));
    }
    __syncthreads();

    // ---- out = s_r*Dr + s_t*Dt (D fp32 still in accumulators) ----
#pragma unroll
    for (int rt = 0; rt < 2; ++rt) {
        int r0c = w * 32 + rt * 16 + hi * 4;
#pragma unroll
        for (int pt = 0; pt < 4; ++pt) {
            int pxb = pt * 16 + lo;
            float sr = sfin[pxb], st = sfin[64 + pxb];
            float* op = out + ((size_t)b * HALF + r0c) * HW + p0 + pxb;
#pragma unroll
            for (int rg = 0; rg < 4; ++rg)
                op[(size_t)rg * HW] = sr * cr[rt][pt][rg] + st * ct[rt][pt][rg];
        }
    }
}

extern "C" void kernel_launch(void* const* d_in, const int* in_sizes, int n_in,
                              void* d_out, int out_size, void* d_ws, size_t ws_size,
                              hipStream_t stream) {
    const float* x    = (const float*)d_in[0];
    const float* Wg   = (const float*)d_in[1];
    const float* bg   = (const float*)d_in[2];
    const float* Wrgb = (const float*)d_in[3];
    const float* brgb = (const float*)d_in[4];
    const float* Wtir = (const float*)d_in[5];
    const float* btir = (const float*)d_in[6];
    const float* Wt1  = (const float*)d_in[7];
    const float* bt1  = (const float*)d_in[8];
    const float* Wt2  = (const float*)d_in[9];
    const float* bt2  = (const float*)d_in[10];
    float* out = (float*)d_out;

    float*          pooled = (float*)d_ws;                              // 8 KiB (atomic sums)
    unsigned short* bw     = (unsigned short*)((char*)d_ws + 8192);     // 400 KiB bf16 weights
    unsigned short* sc     = (unsigned short*)((char*)d_ws + 417792);   // 25 MiB bf16 x frags

    hipMemsetAsync(pooled, 0, NB * CIN * sizeof(float), stream);
    pack_pool_prep_kernel<<<NPACK + 200, 256, 0, stream>>>(x, Wrgb, Wtir, Wt1,
                                                           pooled, bw, sc);
    dim3 grid(NT, NB);
    expert_kernel<<<grid, 256, 0, stream>>>(sc, bw, brgb, btir, bt1, Wt2, bt2,
                                            pooled, Wg, bg, out);
}

// Round 16
// 133.592 us; speedup vs baseline: 1.2186x; 1.0959x over previous
//
#include <hip/hip_runtime.h>

#define HW    6400
#define CIN   256
#define HALF  128
#define QUART 64
#define NB    8
#define NE    5

typedef __attribute__((ext_vector_type(8))) short short8;
typedef __attribute__((ext_vector_type(4))) float f32x4;

__device__ __forceinline__ unsigned short f2bf(float f) {
    unsigned u = __builtin_bit_cast(unsigned, f);
    u = (u + 0x7FFFu + ((u >> 16) & 1u)) >> 16;   // RNE
    return (unsigned short)u;
}

// ---------------- kernel 1: pool (blocks 0..2047) + bf16 weight prep (2048..2247) ----
// bw layout (shorts): [0,81920) Wrgb+I  [81920,163840) Wtir+I  [163840,204800) Wt1
__global__ void pool_prep_kernel(const float* __restrict__ x,
                                 const float* __restrict__ Wrgb, const float* __restrict__ Wtir,
                                 const float* __restrict__ Wt1,
                                 float* __restrict__ pooled, unsigned short* __restrict__ bw) {
    int blk = blockIdx.x;
    if (blk < NB * CIN) {
        const float4* p = reinterpret_cast<const float4*>(x + (size_t)blk * HW);
        float s = 0.f;
        for (int i = threadIdx.x; i < HW / 4; i += 256) {
            float4 v = p[i];
            s += (v.x + v.y) + (v.z + v.w);
        }
        for (int off = 32; off > 0; off >>= 1) s += __shfl_down(s, off, 64);
        __shared__ float wsum[4];
        int wid = threadIdx.x >> 6, lane = threadIdx.x & 63;
        if (lane == 0) wsum[wid] = s;
        __syncthreads();
        if (threadIdx.x == 0)
            pooled[blk] = (wsum[0] + wsum[1] + wsum[2] + wsum[3]) * (1.0f / HW);
    } else {
        int i0 = (blk - NB * CIN) * 1024 + threadIdx.x;
#pragma unroll
        for (int j = 0; j < 4; ++j) {
            int i = i0 + j * 256;
            float v;
            if (i < 81920) {                      // Wrgb + I
                v = Wrgb[i];
                int m = i & 16383;
                if ((m >> 7) == (m & 127)) v += 1.0f;
            } else if (i < 163840) {              // Wtir + I
                int k = i - 81920;
                v = Wtir[k];
                int m = k & 16383;
                if ((m >> 7) == (m & 127)) v += 1.0f;
            } else {
                v = Wt1[i - 163840];
            }
            bw[i] = f2bf(v);
        }
    }
}

// ---------------- kernel 2: gate (per-block, wave 0) + selected-expert MFMA ----------
// LDS frag-linear layout per 128ch x 64px bf16 tile:
//   frag f = kt*4 + pt (kt=ch>>5, pt=px>>4), 1 KiB/frag;
//   lane l = ((ch>>3)&3)*16 + (px&15); byte = f*1024 + l*16 + (ch&7)*2
//   -> B-frag ds_read_b128 at lane*16: conflict-free.
__launch_bounds__(256, 4)
__global__ void expert_kernel(const float* __restrict__ x,
                              const unsigned short* __restrict__ bW,
                              const float* __restrict__ brgb, const float* __restrict__ btir,
                              const float* __restrict__ bt1,
                              const float* __restrict__ Wt2, const float* __restrict__ bt2,
                              const float* __restrict__ pooled,
                              const float* __restrict__ Wg, const float* __restrict__ bg,
                              float* __restrict__ out) {
    __shared__ unsigned short lxr[8192];   // 16 KiB: xr tile -> Dr bf16
    __shared__ unsigned short lxt[8192];   // 16 KiB: xt tile -> Dt bf16
    __shared__ float psum[512];            // wave partials: [ph*256 + w*64 + px]
    __shared__ float sfin[128];            // sigmoid r [0,64) / t [64,128)
    __shared__ int   se;

    const int b    = blockIdx.y;
    const int p0   = blockIdx.x * 64;
    const int t    = threadIdx.x;
    const int w    = __builtin_amdgcn_readfirstlane(t >> 6);
    const int lane = t & 63;
    const int lo   = lane & 15, hi = lane >> 4;

    // ---- stage x -> bf16 frag-linear LDS (both halves) ----
    {
        const int px = t & 63, cb = t >> 6;
        const float* xb = x + (size_t)b * CIN * HW + p0 + px;
        const int li = (px & 15) * 8;
        const int fb = (cb * 4 + (px >> 4)) * 512;
#pragma unroll
        for (int jg = 0; jg < 4; ++jg) {
            unsigned vr[4], vt[4];
#pragma unroll
            for (int jp = 0; jp < 4; ++jp) {
                int ch = cb * 32 + jg * 8 + jp * 2;
                float r0 = xb[(size_t)ch * HW];
                float r1 = xb[(size_t)(ch + 1) * HW];
                float t0 = xb[(size_t)(ch + HALF) * HW];
                float t1 = xb[(size_t)(ch + HALF + 1) * HW];
                vr[jp] = (unsigned)f2bf(r0) | ((unsigned)f2bf(r1) << 16);
                vt[jp] = (unsigned)f2bf(t0) | ((unsigned)f2bf(t1) << 16);
            }
            int si = fb + jg * 128 + li;
            *reinterpret_cast<uint4*>(&lxr[si]) = make_uint4(vr[0], vr[1], vr[2], vr[3]);
            *reinterpret_cast<uint4*>(&lxt[si]) = make_uint4(vt[0], vt[1], vt[2], vt[3]);
        }
    }

    // ---- gate on wave 0 (redundant per block; L2-hot inputs) ----
    if (t < 64) {
        float pv[4];
#pragma unroll
        for (int j = 0; j < 4; ++j) pv[j] = pooled[b * CIN + t * 4 + j];
        float best = -1e30f; int bi = 0;
        for (int e = 0; e < NE; ++e) {
            float part = 0.f;
#pragma unroll
            for (int j = 0; j < 4; ++j) part += pv[j] * Wg[e * CIN + t * 4 + j];
            for (int off = 32; off > 0; off >>= 1) part += __shfl_down(part, off, 64);
            part = __shfl(part, 0, 64);
            float logit = part + bg[e];
            if (logit > best) { best = logit; bi = e; }  // strict > == jnp.argmax
        }
        if (t == 0) se = bi;
    }
    __syncthreads();

    const int e = __builtin_amdgcn_readfirstlane(se);
    const unsigned short* bWrgb = bW + (size_t)e * 16384;
    const unsigned short* bWtir = bW + 81920 + (size_t)e * 16384;
    const unsigned short* bWt1  = bW + 163840 + (size_t)e * 8192;

    // ---- Dr = (Wrgb+I)@xr, Dt = (Wtir+I)@xt ----
    f32x4 cr[2][4], ct[2][4];
    {
        f32x4 z = {0.f, 0.f, 0.f, 0.f};
#pragma unroll
        for (int i = 0; i < 2; ++i)
#pragma unroll
            for (int j = 0; j < 4; ++j) { cr[i][j] = z; ct[i][j] = z; }
    }
#pragma unroll
    for (int kt = 0; kt < 4; ++kt) {
        short8 bR[4], bT[4];
#pragma unroll
        for (int pt = 0; pt < 4; ++pt) {
            bR[pt] = *reinterpret_cast<const short8*>(&lxr[(kt * 4 + pt) * 512 + lane * 8]);
            bT[pt] = *reinterpret_cast<const short8*>(&lxt[(kt * 4 + pt) * 512 + lane * 8]);
        }
#pragma unroll
        for (int rt = 0; rt < 2; ++rt) {
            int row = w * 32 + rt * 16 + lo;
            short8 aR = *reinterpret_cast<const short8*>(&bWrgb[row * 128 + kt * 32 + hi * 8]);
            short8 aT = *reinterpret_cast<const short8*>(&bWtir[row * 128 + kt * 32 + hi * 8]);
#pragma unroll
            for (int pt = 0; pt < 4; ++pt) {
                cr[rt][pt] = __builtin_amdgcn_mfma_f32_16x16x32_bf16(aR, bR[pt], cr[rt][pt], 0, 0, 0);
                ct[rt][pt] = __builtin_amdgcn_mfma_f32_16x16x32_bf16(aT, bT[pt], ct[rt][pt], 0, 0, 0);
            }
        }
    }

    // ---- D += bias (fp32), pack bf16 ----
    uint2 dbr[2][4], dbt[2][4];
#pragma unroll
    for (int rt = 0; rt < 2; ++rt) {
        int r0c = w * 32 + rt * 16 + hi * 4;
        f32x4 biasR = *reinterpret_cast<const f32x4*>(&brgb[e * HALF + r0c]);
        f32x4 biasT = *reinterpret_cast<const f32x4*>(&btir[e * HALF + r0c]);
#pragma unroll
        for (int pt = 0; pt < 4; ++pt) {
#pragma unroll
            for (int rg = 0; rg < 4; ++rg) {
                cr[rt][pt][rg] += biasR[rg];
                ct[rt][pt][rg] += biasT[rg];
            }
            dbr[rt][pt] = make_uint2(
                (unsigned)f2bf(cr[rt][pt][0]) | ((unsigned)f2bf(cr[rt][pt][1]) << 16),
                (unsigned)f2bf(cr[rt][pt][2]) | ((unsigned)f2bf(cr[rt][pt][3]) << 16));
            dbt[rt][pt] = make_uint2(
                (unsigned)f2bf(ct[rt][pt][0]) | ((unsigned)f2bf(ct[rt][pt][1]) << 16),
                (unsigned)f2bf(ct[rt][pt][2]) | ((unsigned)f2bf(ct[rt][pt][3]) << 16));
        }
    }
    __syncthreads();                                   // all GEMM1 B-frag reads done
#pragma unroll
    for (int rt = 0; rt < 2; ++rt) {
        int r0c = w * 32 + rt * 16 + hi * 4;
        int kt2 = r0c >> 5;
        int lp8 = (((r0c >> 3) & 3) * 16 + lo) * 8 + (r0c & 7);
#pragma unroll
        for (int pt = 0; pt < 4; ++pt) {
            int si = (kt2 * 4 + pt) * 512 + lp8;
            *reinterpret_cast<uint2*>(&lxr[si]) = dbr[rt][pt];
            *reinterpret_cast<uint2*>(&lxt[si]) = dbt[rt][pt];
        }
    }
    __syncthreads();                                   // Dr/Dt bf16 visible

    // ---- h = relu(Wt1@D + bt1) for both halves, fragments in registers ----
    f32x4 chr[4], cht[4];
    {
        f32x4 z = {0.f, 0.f, 0.f, 0.f};
#pragma unroll
        for (int j = 0; j < 4; ++j) { chr[j] = z; cht[j] = z; }
    }
#pragma unroll
    for (int kt = 0; kt < 4; ++kt) {
        int row = w * 16 + lo;
        short8 aH = *reinterpret_cast<const short8*>(&bWt1[row * 128 + kt * 32 + hi * 8]);
#pragma unroll
        for (int pt = 0; pt < 4; ++pt) {
            short8 bDr = *reinterpret_cast<const short8*>(&lxr[(kt * 4 + pt) * 512 + lane * 8]);
            short8 bDt = *reinterpret_cast<const short8*>(&lxt[(kt * 4 + pt) * 512 + lane * 8]);
            chr[pt] = __builtin_amdgcn_mfma_f32_16x16x32_bf16(aH, bDr, chr[pt], 0, 0, 0);
            cht[pt] = __builtin_amdgcn_mfma_f32_16x16x32_bf16(aH, bDt, cht[pt], 0, 0, 0);
        }
    }

    // ---- Wt2·h in-register: 4 FMA + butterfly over hi, psum over waves ----
    {
        int m0 = w * 16 + hi * 4;
        f32x4 b1  = *reinterpret_cast<const f32x4*>(&bt1[e * QUART + m0]);
        f32x4 w2v = *reinterpret_cast<const f32x4*>(&Wt2[e * QUART + m0]);
#pragma unroll
        for (int pt = 0; pt < 4; ++pt) {
            float pr = 0.f, ptt = 0.f;
#pragma unroll
            for (int rg = 0; rg < 4; ++rg) {
                pr  = fmaf(w2v[rg], fmaxf(chr[pt][rg] + b1[rg], 0.f), pr);
                ptt = fmaf(w2v[rg], fmaxf(cht[pt][rg] + b1[rg], 0.f), ptt);
            }
            pr  += __shfl_xor(pr, 16, 64);  pr  += __shfl_xor(pr, 32, 64);
            ptt += __shfl_xor(ptt, 16, 64); ptt += __shfl_xor(ptt, 32, 64);
            if (hi == 0) {
                psum[w * 64 + pt * 16 + lo]       = pr;
                psum[256 + w * 64 + pt * 16 + lo] = ptt;
            }
        }
    }
    __syncthreads();
    if (t < 128) {
        int ph = t >> 6, px = t & 63;
        const float* ps = &psum[ph * 256];
        float a = ps[px] + ps[64 + px] + ps[128 + px] + ps[192 + px] + bt2[e];
        sfin[t] = 1.f / (1.f + __expf(-a));
    }
    __syncthreads();

    // ---- out = s_r*Dr + s_t*Dt (D fp32 still in accumulators) ----
#pragma unroll
    for (int rt = 0; rt < 2; ++rt) {
        int r0c = w * 32 + rt * 16 + hi * 4;
#pragma unroll
        for (int pt = 0; pt < 4; ++pt) {
            int pxb = pt * 16 + lo;
            float sr = sfin[pxb], st = sfin[64 + pxb];
            float* op = out + ((size_t)b * HALF + r0c) * HW + p0 + pxb;
#pragma unroll
            for (int rg = 0; rg < 4; ++rg)
                op[(size_t)rg * HW] = sr * cr[rt][pt][rg] + st * ct[rt][pt][rg];
        }
    }
}

extern "C" void kernel_launch(void* const* d_in, const int* in_sizes, int n_in,
                              void* d_out, int out_size, void* d_ws, size_t ws_size,
                              hipStream_t stream) {
    const float* x    = (const float*)d_in[0];
    const float* Wg   = (const float*)d_in[1];
    const float* bg   = (const float*)d_in[2];
    const float* Wrgb = (const float*)d_in[3];
    const float* brgb = (const float*)d_in[4];
    const float* Wtir = (const float*)d_in[5];
    const float* btir = (const float*)d_in[6];
    const float* Wt1  = (const float*)d_in[7];
    const float* bt1  = (const float*)d_in[8];
    const float* Wt2  = (const float*)d_in[9];
    const float* bt2  = (const float*)d_in[10];
    float* out = (float*)d_out;

    float*          pooled = (float*)d_ws;                          // 8 KiB
    unsigned short* bw     = (unsigned short*)((char*)d_ws + 8192); // 400 KiB bf16 weights

    pool_prep_kernel<<<NB * CIN + 200, 256, 0, stream>>>(x, Wrgb, Wtir, Wt1, pooled, bw);
    dim3 grid(100, NB);
    expert_kernel<<<grid, 256, 0, stream>>>(x, bw, brgb, btir, bt1, Wt2, bt2,
                                            pooled, Wg, bg, out);
}